// Round 3
// baseline (554.989 us; speedup 1.0000x reference)
//
#include <hip/hip_runtime.h>

typedef __bf16 bf16;
typedef __attribute__((ext_vector_type(8))) __bf16 bf16x8;
typedef __attribute__((ext_vector_type(4))) float f32x4;

#define HH 256
#define WW 256
#define NPIX 65536

__device__ inline bf16x8 bzero8() {
    bf16x8 v;
    #pragma unroll
    for (int i = 0; i < 8; ++i) v[i] = (bf16)0.0f;
    return v;
}

// ---------------------------------------------------------------------------
// input NCHW fp32 -> NHWC bf16
// ---------------------------------------------------------------------------
__global__ __launch_bounds__(256) void prep_in(const float* __restrict__ in,
                                               bf16* __restrict__ out) {
    int p = blockIdx.x * 256 + threadIdx.x;
    int b = p >> 16, rem = p & 65535;
    #pragma unroll
    for (int cg = 0; cg < 4; ++cg) {
        bf16x8 v;
        #pragma unroll
        for (int j = 0; j < 8; ++j)
            v[j] = (bf16)in[(size_t)(b * 32 + cg * 8 + j) * NPIX + rem];
        *reinterpret_cast<bf16x8*>(out + (size_t)p * 32 + cg * 8) = v;
    }
}

// ---------------------------------------------------------------------------
// Fold BN into conv weights; core weights [tap][nn][ci]; final weights
// [chunk(r) 4][tap 9][co 32][ci_slot 32] with ci_slot -> true-channel perm
// matching core_pred's pred channel-slot layout.
// ---------------------------------------------------------------------------
__global__ void fold_w(const float* __restrict__ wconv, const float* __restrict__ bconv,
                       const float* __restrict__ g, const float* __restrict__ beta,
                       const float* __restrict__ mu, const float* __restrict__ var,
                       const float* __restrict__ w_outc, const float* __restrict__ w_final,
                       bf16* __restrict__ Wres, float* __restrict__ Bres,
                       bf16* __restrict__ Wcore, bf16* __restrict__ Wfin) {
    int idx = blockIdx.x * 256 + threadIdx.x;
    if (idx < 73728) {
        int l = idx / 9216, r = idx % 9216;
        int tap = r >> 10, co = (r >> 5) & 31, ci = r & 31;
        float s = g[l * 32 + co] * rsqrtf(var[l * 32 + co] + 1e-5f);
        Wres[idx] = (bf16)(wconv[l * 9216 + (co * 32 + ci) * 9 + tap] * s);
    } else if (idx < 73984) {
        int i = idx - 73728;
        float s = g[i] * rsqrtf(var[i] + 1e-5f);
        Bres[i] = (bconv[i] - mu[i]) * s + beta[i];
    } else if (idx < 83200) {
        int r = idx - 73984;
        int tap = r >> 10, nn = (r >> 5) & 31, ci = r & 31;
        Wcore[r] = (bf16)w_outc[(nn * 9 + tap) * 32 + ci];
    } else if (idx < 120064) {
        int r = idx - 83200;
        int chunk = r / 9216, r2 = r % 9216;
        int tap = r2 >> 10, co = (r2 >> 5) & 31, ci = r2 & 31;
        int c = ci >> 3, j = ci & 7;
        int n = 4 * c + (j >> 1) + 16 * (j & 1);   // slot -> true channel
        Wfin[r] = (bf16)w_final[(size_t)(co * 128 + chunk * 32 + n) * 9 + tap];
    }
}

// ---------------------------------------------------------------------------
// conv3x3 (32->32) MFMA implicit GEMM, NHWC bf16, BN folded, +resid, ReLU
// ---------------------------------------------------------------------------
template <bool RESID>
__global__ __launch_bounds__(256) void conv3x3_mfma(
    const bf16* __restrict__ in, const bf16* __restrict__ wB,
    const float* __restrict__ bias, const bf16* __restrict__ resid,
    bf16* __restrict__ out) {
    __shared__ bf16 tile[10 * 66 * 40];
    const int x0 = blockIdx.x * 64, y0 = blockIdx.y * 8, b = blockIdx.z;
    const int tid = threadIdx.x;
    const int lane = tid & 63, wv = tid >> 6;
    const int col = lane & 15, gq = lane >> 4;

    bf16x8 Bf[9][2];
    #pragma unroll
    for (int tap = 0; tap < 9; ++tap)
        #pragma unroll
        for (int cb = 0; cb < 2; ++cb)
            Bf[tap][cb] = *reinterpret_cast<const bf16x8*>(
                wB + tap * 1024 + (cb * 16 + col) * 32 + gq * 8);
    const float b0 = bias[col], b1 = bias[16 + col];

    const bf16* inb = in + (size_t)b * NPIX * 32;
    for (int i = tid; i < 2640; i += 256) {
        int yy = i / 264, r = i % 264;
        int xx = r >> 2, cg = r & 3;
        int gy = y0 + yy - 1, gx = x0 + xx - 1;
        bf16x8 v = bzero8();
        if ((unsigned)gy < HH && (unsigned)gx < WW)
            v = *reinterpret_cast<const bf16x8*>(inb + ((size_t)gy * WW + gx) * 32 + cg * 8);
        *reinterpret_cast<bf16x8*>(&tile[(yy * 66 + xx) * 40 + cg * 8]) = v;
    }

    f32x4 acc[8][2];
    #pragma unroll
    for (int m = 0; m < 8; ++m) {
        acc[m][0] = {b0, b0, b0, b0};
        acc[m][1] = {b1, b1, b1, b1};
    }
    __syncthreads();

    #pragma unroll
    for (int m = 0; m < 8; ++m) {
        const int row = 2 * wv + (m >> 2), xb = m & 3;
        #pragma unroll
        for (int tap = 0; tap < 9; ++tap) {
            const int dy = tap / 3, dx = tap % 3;
            bf16x8 A = *reinterpret_cast<const bf16x8*>(
                &tile[((row + dy) * 66 + xb * 16 + col + dx) * 40 + gq * 8]);
            acc[m][0] = __builtin_amdgcn_mfma_f32_16x16x32_bf16(A, Bf[tap][0], acc[m][0], 0, 0, 0);
            acc[m][1] = __builtin_amdgcn_mfma_f32_16x16x32_bf16(A, Bf[tap][1], acc[m][1], 0, 0, 0);
        }
    }

    bf16* outb = out + (size_t)b * NPIX * 32;
    const bf16* resb = RESID ? (resid + (size_t)b * NPIX * 32) : nullptr;
    #pragma unroll
    for (int m = 0; m < 8; ++m) {
        const int y = y0 + 2 * wv + (m >> 2);
        const int xbase = x0 + (m & 3) * 16 + gq * 4;
        #pragma unroll
        for (int cb = 0; cb < 2; ++cb) {
            const int co = cb * 16 + col;
            #pragma unroll
            for (int j = 0; j < 4; ++j) {
                size_t a = ((size_t)y * WW + xbase + j) * 32 + co;
                float v = acc[m][cb][j];
                if (RESID) v += (float)resb[a];
                outb[a] = (bf16)fmaxf(v, 0.0f);
            }
        }
    }
}

// ---------------------------------------------------------------------------
// final conv3x3 (128->32), 4 ci-chunks, out fp32 NCHW
// ---------------------------------------------------------------------------
__global__ __launch_bounds__(256) void final_conv_mfma(
    const bf16* __restrict__ pred, const bf16* __restrict__ Wfin,
    const float* __restrict__ bfin, float* __restrict__ out) {
    __shared__ bf16 tile[10 * 66 * 40];
    const int x0 = blockIdx.x * 64, y0 = blockIdx.y * 8, b = blockIdx.z;
    const int tid = threadIdx.x;
    const int lane = tid & 63, wv = tid >> 6;
    const int col = lane & 15, gq = lane >> 4;

    const float b0 = bfin[col], b1 = bfin[16 + col];
    f32x4 acc[8][2];
    #pragma unroll
    for (int m = 0; m < 8; ++m) {
        acc[m][0] = {b0, b0, b0, b0};
        acc[m][1] = {b1, b1, b1, b1};
    }

    for (int chunk = 0; chunk < 4; ++chunk) {
        if (chunk) __syncthreads();
        const bf16* inb = pred + (size_t)b * NPIX * 128 + chunk * 32;
        for (int i = tid; i < 2640; i += 256) {
            int yy = i / 264, r = i % 264;
            int xx = r >> 2, cg = r & 3;
            int gy = y0 + yy - 1, gx = x0 + xx - 1;
            bf16x8 v = bzero8();
            if ((unsigned)gy < HH && (unsigned)gx < WW)
                v = *reinterpret_cast<const bf16x8*>(inb + ((size_t)gy * WW + gx) * 128 + cg * 8);
            *reinterpret_cast<bf16x8*>(&tile[(yy * 66 + xx) * 40 + cg * 8]) = v;
        }
        bf16x8 Bf[9][2];
        #pragma unroll
        for (int tap = 0; tap < 9; ++tap)
            #pragma unroll
            for (int cb = 0; cb < 2; ++cb)
                Bf[tap][cb] = *reinterpret_cast<const bf16x8*>(
                    Wfin + chunk * 9216 + tap * 1024 + (cb * 16 + col) * 32 + gq * 8);
        __syncthreads();

        #pragma unroll
        for (int m = 0; m < 8; ++m) {
            const int row = 2 * wv + (m >> 2), xb = m & 3;
            #pragma unroll
            for (int tap = 0; tap < 9; ++tap) {
                const int dy = tap / 3, dx = tap % 3;
                bf16x8 A = *reinterpret_cast<const bf16x8*>(
                    &tile[((row + dy) * 66 + xb * 16 + col + dx) * 40 + gq * 8]);
                acc[m][0] = __builtin_amdgcn_mfma_f32_16x16x32_bf16(A, Bf[tap][0], acc[m][0], 0, 0, 0);
                acc[m][1] = __builtin_amdgcn_mfma_f32_16x16x32_bf16(A, Bf[tap][1], acc[m][1], 0, 0, 0);
            }
        }
    }

    #pragma unroll
    for (int m = 0; m < 8; ++m) {
        const int y = y0 + 2 * wv + (m >> 2);
        const int xbase = x0 + (m & 3) * 16 + gq * 4;
        #pragma unroll
        for (int cb = 0; cb < 2; ++cb) {
            const int co = cb * 16 + col;
            #pragma unroll
            for (int j = 0; j < 4; ++j)
                out[(size_t)(b * 32 + co) * NPIX + (size_t)y * WW + xbase + j] = acc[m][cb][j];
        }
    }
}

// ---------------------------------------------------------------------------
// core_pred v2: 64x4 tile, 512 threads, 2 blocks/CU.
// Phase A (per tap): MFMA core (A=m5 from global, B=Wcore) -> packed b32
//   writes into wave-private core_lds rows (no barriers needed).
// Phase B: lane = (px offset = lane&15, cg = lane>>4); all reads b128:
//   core_lds [256 px][pitch 80B], frames planes [4][12*72][16B] with
//   interleaved channel perm (4c,4c+16,4c+1,4c+17,...).
// pred out channel slot r*32+cg*8+k holds true channel perm (matched by Wfin).
// ---------------------------------------------------------------------------
__global__ __launch_bounds__(512, 4) void core_pred_v2(
    const bf16* __restrict__ m, const bf16* __restrict__ frames,
    const float* __restrict__ tau, const bf16* __restrict__ Wcore,
    const float* __restrict__ b_outc, bf16* __restrict__ pred) {
    extern __shared__ char smem[];
    bf16* fr    = (bf16*)smem;             // 4 planes * 864 px * 8 ch = 55296 B
    char* coreb = smem + 55296;            // 256 px * 80 B = 20480 B
    const int x0 = blockIdx.x * 64, y0 = blockIdx.y * 4, b = blockIdx.z;
    const int tid = threadIdx.x;
    const int lane = tid & 63, w = tid >> 6;
    const int col = lane & 15, g = lane >> 4;

    // ---- stage frames planes (perm'd channels) ----
    const bf16* fb = frames + (size_t)b * NPIX * 32;
    for (int i = tid; i < 3456; i += 512) {          // 864 px * 4 planes
        int px = i >> 2, c = i & 3;
        int rr = px / 72, cc = px % 72;
        int gy = y0 + rr - 4, gx = x0 + cc - 4;
        bf16x8 lo = bzero8(), hi = bzero8();
        if ((unsigned)gy < HH && (unsigned)gx < WW) {
            const bf16* p = fb + ((size_t)gy * WW + gx) * 32;
            lo = *reinterpret_cast<const bf16x8*>(p + (c >> 1) * 8);
            hi = *reinterpret_cast<const bf16x8*>(p + 16 + (c >> 1) * 8);
        }
        const int sel = (c & 1) * 4;
        bf16x8 o;
        #pragma unroll
        for (int k = 0; k < 4; ++k) {
            o[2 * k]     = lo[sel + k];
            o[2 * k + 1] = hi[sel + k];
        }
        *reinterpret_cast<bf16x8*>(fr + c * 6912 + px * 8) = o;
    }

    // ---- A fragments (m5 = relu(m - tau)) straight from global ----
    float t8[8];
    #pragma unroll
    for (int k = 0; k < 8; ++k) t8[k] = tau[g * 8 + k];
    const bf16* mb = m + (size_t)b * NPIX * 32;
    bf16x8 A[2];
    #pragma unroll
    for (int u = 0; u < 2; ++u) {
        int px = (w * 2 + u) * 16 + col;
        int y = y0 + (px >> 6), x = x0 + (px & 63);
        bf16x8 v = *reinterpret_cast<const bf16x8*>(mb + ((size_t)y * WW + x) * 32 + g * 8);
        #pragma unroll
        for (int k = 0; k < 8; ++k)
            v[k] = (bf16)fmaxf((float)v[k] - t8[k], 0.0f);
        A[u] = v;
    }
    __syncthreads();

    float acc[2][4][8];
    #pragma unroll
    for (int u = 0; u < 2; ++u)
        #pragma unroll
        for (int r = 0; r < 4; ++r)
            #pragma unroll
            for (int k = 0; k < 8; ++k) acc[u][r][k] = 0.0f;

    #pragma unroll
    for (int tap = 0; tap < 9; ++tap) {
        const int dy = tap / 3 - 1, dx = tap % 3 - 1;
        bf16x8 B0 = *reinterpret_cast<const bf16x8*>(Wcore + tap * 1024 + col * 32 + g * 8);
        bf16x8 B1 = *reinterpret_cast<const bf16x8*>(Wcore + tap * 1024 + (16 + col) * 32 + g * 8);
        const float bv0 = b_outc[col * 9 + tap];
        const float bv1 = b_outc[(16 + col) * 9 + tap];

        #pragma unroll
        for (int u = 0; u < 2; ++u) {
            f32x4 c0 = {bv0, bv0, bv0, bv0};
            f32x4 c1 = {bv1, bv1, bv1, bv1};
            c0 = __builtin_amdgcn_mfma_f32_16x16x32_bf16(A[u], B0, c0, 0, 0, 0);
            c1 = __builtin_amdgcn_mfma_f32_16x16x32_bf16(A[u], B1, c1, 0, 0, 0);
            #pragma unroll
            for (int j = 0; j < 4; ++j) {
                union { unsigned uu; bf16 h[2]; } pk;
                pk.h[0] = (bf16)c0[j];
                pk.h[1] = (bf16)c1[j];
                int px = (w * 2 + u) * 16 + g * 4 + j;
                *reinterpret_cast<unsigned*>(coreb + px * 80 + col * 4) = pk.uu;
            }
        }

        // same-wave LDS write->read ordering is guaranteed (wave-private rows)
        #pragma unroll
        for (int u = 0; u < 2; ++u) {
            const int px = (w * 2 + u) * 16 + col;
            const int py = px >> 6, pxx = px & 63;
            bf16x8 c8 = *reinterpret_cast<const bf16x8*>(coreb + px * 80 + g * 16);
            float cf[8];
            #pragma unroll
            for (int k = 0; k < 8; ++k) cf[k] = (float)c8[k];
            #pragma unroll
            for (int r = 0; r < 4; ++r) {
                const int R = r + 1;
                const int row = py + 4 + dy * R, ccl = pxx + 4 + dx * R;
                bf16x8 f8 = *reinterpret_cast<const bf16x8*>(fr + g * 6912 + (row * 72 + ccl) * 8);
                #pragma unroll
                for (int k = 0; k < 8; ++k)
                    acc[u][r][k] += cf[k] * (float)f8[k];
            }
        }
    }

    bf16* pb = pred + (size_t)b * NPIX * 128;
    #pragma unroll
    for (int u = 0; u < 2; ++u) {
        const int px = (w * 2 + u) * 16 + col;
        const int y = y0 + (px >> 6), x = x0 + (px & 63);
        #pragma unroll
        for (int r = 0; r < 4; ++r) {
            bf16x8 o;
            #pragma unroll
            for (int k = 0; k < 8; ++k) o[k] = (bf16)acc[u][r][k];
            *reinterpret_cast<bf16x8*>(pb + ((size_t)y * WW + x) * 128 + r * 32 + g * 8) = o;
        }
    }
}

// ---------------------------------------------------------------------------
extern "C" void kernel_launch(void* const* d_in, const int* in_sizes, int n_in,
                              void* d_out, int out_size, void* d_ws, size_t ws_size,
                              hipStream_t stream) {
    const float* input    = (const float*)d_in[0];
    const float* wconv    = (const float*)d_in[1];
    const float* bconv    = (const float*)d_in[2];
    const float* bn_gamma = (const float*)d_in[3];
    const float* bn_beta  = (const float*)d_in[4];
    const float* bn_mean  = (const float*)d_in[5];
    const float* bn_var   = (const float*)d_in[6];
    const float* tau      = (const float*)d_in[7];
    const float* w_outc   = (const float*)d_in[8];
    const float* b_outc   = (const float*)d_in[9];
    const float* w_final  = (const float*)d_in[10];
    const float* b_final  = (const float*)d_in[11];
    float* out = (float*)d_out;

    char* ws = (char*)d_ws;
    bf16*  Wres  = (bf16*)(ws);
    float* Bres  = (float*)(ws + 147456);
    bf16*  Wcore = (bf16*)(ws + 148480);
    bf16*  Wfin  = (bf16*)(ws + 166912);
    bf16*  in0b  = (bf16*)(ws + 240640);
    bf16*  actA  = (bf16*)(ws + 240640 + 16777216ull);
    bf16*  actB  = (bf16*)(ws + 240640 + 2 * 16777216ull);
    bf16*  actC  = (bf16*)(ws + 240640 + 3 * 16777216ull);
    bf16*  pred  = (bf16*)(ws + 240640 + 4 * 16777216ull);

    hipFuncSetAttribute(reinterpret_cast<const void*>(&core_pred_v2),
                        hipFuncAttributeMaxDynamicSharedMemorySize, 75776);

    prep_in<<<1024, 256, 0, stream>>>(input, in0b);
    fold_w<<<470, 256, 0, stream>>>(wconv, bconv, bn_gamma, bn_beta, bn_mean, bn_var,
                                    w_outc, w_final, Wres, Bres, Wcore, Wfin);

    dim3 grid(4, 32, 4), blk(256);
    conv3x3_mfma<false><<<grid, blk, 0, stream>>>(in0b, Wres + 0 * 9216, Bres + 0,   nullptr, actA);
    conv3x3_mfma<true ><<<grid, blk, 0, stream>>>(actA, Wres + 1 * 9216, Bres + 32,  in0b,    actB);
    conv3x3_mfma<false><<<grid, blk, 0, stream>>>(actB, Wres + 2 * 9216, Bres + 64,  nullptr, actA);
    conv3x3_mfma<true ><<<grid, blk, 0, stream>>>(actA, Wres + 3 * 9216, Bres + 96,  actB,    actC);
    conv3x3_mfma<false><<<grid, blk, 0, stream>>>(actC, Wres + 4 * 9216, Bres + 128, nullptr, actA);
    conv3x3_mfma<true ><<<grid, blk, 0, stream>>>(actA, Wres + 5 * 9216, Bres + 160, actC,    actB);
    conv3x3_mfma<false><<<grid, blk, 0, stream>>>(actB, Wres + 6 * 9216, Bres + 192, nullptr, actA);
    conv3x3_mfma<true ><<<grid, blk, 0, stream>>>(actA, Wres + 7 * 9216, Bres + 224, actB,    actC);

    dim3 gridp(4, 64, 4), blkp(512);
    core_pred_v2<<<gridp, blkp, 75776, stream>>>(actC, in0b, tau, Wcore, b_outc, pred);

    final_conv_mfma<<<grid, blk, 0, stream>>>(pred, Wfin, b_final, out);
}

// Round 4
// 303.477 us; speedup vs baseline: 1.8288x; 1.8288x over previous
//
#include <hip/hip_runtime.h>

typedef __bf16 bf16;
typedef __attribute__((ext_vector_type(8))) __bf16 bf16x8;
typedef __attribute__((ext_vector_type(4))) float f32x4;

#define HH 256
#define WW 256
#define NPIX 65536

__device__ inline bf16x8 bzero8() {
    bf16x8 v;
    #pragma unroll
    for (int i = 0; i < 8; ++i) v[i] = (bf16)0.0f;
    return v;
}

// ---------------------------------------------------------------------------
// input NCHW fp32 -> NHWC bf16
// ---------------------------------------------------------------------------
__global__ __launch_bounds__(256) void prep_in(const float* __restrict__ in,
                                               bf16* __restrict__ out) {
    int p = blockIdx.x * 256 + threadIdx.x;
    int b = p >> 16, rem = p & 65535;
    #pragma unroll
    for (int cg = 0; cg < 4; ++cg) {
        bf16x8 v;
        #pragma unroll
        for (int j = 0; j < 8; ++j)
            v[j] = (bf16)in[(size_t)(b * 32 + cg * 8 + j) * NPIX + rem];
        *reinterpret_cast<bf16x8*>(out + (size_t)p * 32 + cg * 8) = v;
    }
}

// ---------------------------------------------------------------------------
// Fold BN into conv weights; core weights [tap][nn][ci]; final weights
// [chunk(r) 4][tap 9][co 32][ci_slot 32] with ci_slot -> true-channel perm
// matching core_pred's pred channel-slot layout.
// ---------------------------------------------------------------------------
__global__ void fold_w(const float* __restrict__ wconv, const float* __restrict__ bconv,
                       const float* __restrict__ g, const float* __restrict__ beta,
                       const float* __restrict__ mu, const float* __restrict__ var,
                       const float* __restrict__ w_outc, const float* __restrict__ w_final,
                       bf16* __restrict__ Wres, float* __restrict__ Bres,
                       bf16* __restrict__ Wcore, bf16* __restrict__ Wfin) {
    int idx = blockIdx.x * 256 + threadIdx.x;
    if (idx < 73728) {
        int l = idx / 9216, r = idx % 9216;
        int tap = r >> 10, co = (r >> 5) & 31, ci = r & 31;
        float s = g[l * 32 + co] * rsqrtf(var[l * 32 + co] + 1e-5f);
        Wres[idx] = (bf16)(wconv[l * 9216 + (co * 32 + ci) * 9 + tap] * s);
    } else if (idx < 73984) {
        int i = idx - 73728;
        float s = g[i] * rsqrtf(var[i] + 1e-5f);
        Bres[i] = (bconv[i] - mu[i]) * s + beta[i];
    } else if (idx < 83200) {
        int r = idx - 73984;
        int tap = r >> 10, nn = (r >> 5) & 31, ci = r & 31;
        Wcore[r] = (bf16)w_outc[(nn * 9 + tap) * 32 + ci];
    } else if (idx < 120064) {
        int r = idx - 83200;
        int chunk = r / 9216, r2 = r % 9216;
        int tap = r2 >> 10, co = (r2 >> 5) & 31, ci = r2 & 31;
        int c = ci >> 3, j = ci & 7;
        int n = 4 * c + (j >> 1) + 16 * (j & 1);   // slot -> true channel
        Wfin[r] = (bf16)w_final[(size_t)(co * 128 + chunk * 32 + n) * 9 + tap];
    }
}

// ---------------------------------------------------------------------------
// conv3x3 (32->32) MFMA implicit GEMM, NHWC bf16, BN folded, +resid, ReLU
// ---------------------------------------------------------------------------
template <bool RESID>
__global__ __launch_bounds__(256) void conv3x3_mfma(
    const bf16* __restrict__ in, const bf16* __restrict__ wB,
    const float* __restrict__ bias, const bf16* __restrict__ resid,
    bf16* __restrict__ out) {
    __shared__ bf16 tile[10 * 66 * 40];
    const int x0 = blockIdx.x * 64, y0 = blockIdx.y * 8, b = blockIdx.z;
    const int tid = threadIdx.x;
    const int lane = tid & 63, wv = tid >> 6;
    const int col = lane & 15, gq = lane >> 4;

    bf16x8 Bf[9][2];
    #pragma unroll
    for (int tap = 0; tap < 9; ++tap)
        #pragma unroll
        for (int cb = 0; cb < 2; ++cb)
            Bf[tap][cb] = *reinterpret_cast<const bf16x8*>(
                wB + tap * 1024 + (cb * 16 + col) * 32 + gq * 8);
    const float b0 = bias[col], b1 = bias[16 + col];

    const bf16* inb = in + (size_t)b * NPIX * 32;
    for (int i = tid; i < 2640; i += 256) {
        int yy = i / 264, r = i % 264;
        int xx = r >> 2, cg = r & 3;
        int gy = y0 + yy - 1, gx = x0 + xx - 1;
        bf16x8 v = bzero8();
        if ((unsigned)gy < HH && (unsigned)gx < WW)
            v = *reinterpret_cast<const bf16x8*>(inb + ((size_t)gy * WW + gx) * 32 + cg * 8);
        *reinterpret_cast<bf16x8*>(&tile[(yy * 66 + xx) * 40 + cg * 8]) = v;
    }

    f32x4 acc[8][2];
    #pragma unroll
    for (int m = 0; m < 8; ++m) {
        acc[m][0] = {b0, b0, b0, b0};
        acc[m][1] = {b1, b1, b1, b1};
    }
    __syncthreads();

    #pragma unroll
    for (int m = 0; m < 8; ++m) {
        const int row = 2 * wv + (m >> 2), xb = m & 3;
        #pragma unroll
        for (int tap = 0; tap < 9; ++tap) {
            const int dy = tap / 3, dx = tap % 3;
            bf16x8 A = *reinterpret_cast<const bf16x8*>(
                &tile[((row + dy) * 66 + xb * 16 + col + dx) * 40 + gq * 8]);
            acc[m][0] = __builtin_amdgcn_mfma_f32_16x16x32_bf16(A, Bf[tap][0], acc[m][0], 0, 0, 0);
            acc[m][1] = __builtin_amdgcn_mfma_f32_16x16x32_bf16(A, Bf[tap][1], acc[m][1], 0, 0, 0);
        }
    }

    bf16* outb = out + (size_t)b * NPIX * 32;
    const bf16* resb = RESID ? (resid + (size_t)b * NPIX * 32) : nullptr;
    #pragma unroll
    for (int m = 0; m < 8; ++m) {
        const int y = y0 + 2 * wv + (m >> 2);
        const int xbase = x0 + (m & 3) * 16 + gq * 4;
        #pragma unroll
        for (int cb = 0; cb < 2; ++cb) {
            const int co = cb * 16 + col;
            #pragma unroll
            for (int j = 0; j < 4; ++j) {
                size_t a = ((size_t)y * WW + xbase + j) * 32 + co;
                float v = acc[m][cb][j];
                if (RESID) v += (float)resb[a];
                outb[a] = (bf16)fmaxf(v, 0.0f);
            }
        }
    }
}

// ---------------------------------------------------------------------------
// final conv3x3 (128->32), 4 ci-chunks, out fp32 NCHW
// ---------------------------------------------------------------------------
__global__ __launch_bounds__(256) void final_conv_mfma(
    const bf16* __restrict__ pred, const bf16* __restrict__ Wfin,
    const float* __restrict__ bfin, float* __restrict__ out) {
    __shared__ bf16 tile[10 * 66 * 40];
    const int x0 = blockIdx.x * 64, y0 = blockIdx.y * 8, b = blockIdx.z;
    const int tid = threadIdx.x;
    const int lane = tid & 63, wv = tid >> 6;
    const int col = lane & 15, gq = lane >> 4;

    const float b0 = bfin[col], b1 = bfin[16 + col];
    f32x4 acc[8][2];
    #pragma unroll
    for (int m = 0; m < 8; ++m) {
        acc[m][0] = {b0, b0, b0, b0};
        acc[m][1] = {b1, b1, b1, b1};
    }

    for (int chunk = 0; chunk < 4; ++chunk) {
        if (chunk) __syncthreads();
        const bf16* inb = pred + (size_t)b * NPIX * 128 + chunk * 32;
        for (int i = tid; i < 2640; i += 256) {
            int yy = i / 264, r = i % 264;
            int xx = r >> 2, cg = r & 3;
            int gy = y0 + yy - 1, gx = x0 + xx - 1;
            bf16x8 v = bzero8();
            if ((unsigned)gy < HH && (unsigned)gx < WW)
                v = *reinterpret_cast<const bf16x8*>(inb + ((size_t)gy * WW + gx) * 128 + cg * 8);
            *reinterpret_cast<bf16x8*>(&tile[(yy * 66 + xx) * 40 + cg * 8]) = v;
        }
        bf16x8 Bf[9][2];
        #pragma unroll
        for (int tap = 0; tap < 9; ++tap)
            #pragma unroll
            for (int cb = 0; cb < 2; ++cb)
                Bf[tap][cb] = *reinterpret_cast<const bf16x8*>(
                    Wfin + chunk * 9216 + tap * 1024 + (cb * 16 + col) * 32 + gq * 8);
        __syncthreads();

        #pragma unroll
        for (int m = 0; m < 8; ++m) {
            const int row = 2 * wv + (m >> 2), xb = m & 3;
            #pragma unroll
            for (int tap = 0; tap < 9; ++tap) {
                const int dy = tap / 3, dx = tap % 3;
                bf16x8 A = *reinterpret_cast<const bf16x8*>(
                    &tile[((row + dy) * 66 + xb * 16 + col + dx) * 40 + gq * 8]);
                acc[m][0] = __builtin_amdgcn_mfma_f32_16x16x32_bf16(A, Bf[tap][0], acc[m][0], 0, 0, 0);
                acc[m][1] = __builtin_amdgcn_mfma_f32_16x16x32_bf16(A, Bf[tap][1], acc[m][1], 0, 0, 0);
            }
        }
    }

    #pragma unroll
    for (int m = 0; m < 8; ++m) {
        const int y = y0 + 2 * wv + (m >> 2);
        const int xbase = x0 + (m & 3) * 16 + gq * 4;
        #pragma unroll
        for (int cb = 0; cb < 2; ++cb) {
            const int co = cb * 16 + col;
            #pragma unroll
            for (int j = 0; j < 4; ++j)
                out[(size_t)(b * 32 + co) * NPIX + (size_t)y * WW + xbase + j] = acc[m][cb][j];
        }
    }
}

// ---------------------------------------------------------------------------
// core_pred v3: 64x4 tile, 512 threads, 2 blocks/CU (launch_bounds (512,2)
// -> 128 VGPR cap). Rate-split outer loop halves the accumulator to 32 regs
// so nothing spills. Frames plane stride 6920 (bank-staggered).
// ---------------------------------------------------------------------------
__global__ __launch_bounds__(512, 2) void core_pred_v3(
    const bf16* __restrict__ m, const bf16* __restrict__ frames,
    const float* __restrict__ tau, const bf16* __restrict__ Wcore,
    const float* __restrict__ b_outc, bf16* __restrict__ pred) {
    extern __shared__ char smem[];
    bf16* fr    = (bf16*)smem;             // 4 planes * stride 6920 el = 55360 B
    char* coreb = smem + 55360;            // 256 px * 80 B = 20480 B
    const int x0 = blockIdx.x * 64, y0 = blockIdx.y * 4, b = blockIdx.z;
    const int tid = threadIdx.x;
    const int lane = tid & 63, w = tid >> 6;
    const int col = lane & 15, g = lane >> 4;

    // ---- stage frames planes (perm'd channels) ----
    const bf16* fb = frames + (size_t)b * NPIX * 32;
    for (int i = tid; i < 3456; i += 512) {          // 864 px * 4 planes
        int px = i >> 2, c = i & 3;
        int rr = px / 72, cc = px % 72;
        int gy = y0 + rr - 4, gx = x0 + cc - 4;
        bf16x8 lo = bzero8(), hi = bzero8();
        if ((unsigned)gy < HH && (unsigned)gx < WW) {
            const bf16* p = fb + ((size_t)gy * WW + gx) * 32;
            lo = *reinterpret_cast<const bf16x8*>(p + (c >> 1) * 8);
            hi = *reinterpret_cast<const bf16x8*>(p + 16 + (c >> 1) * 8);
        }
        const int sel = (c & 1) * 4;
        bf16x8 o;
        #pragma unroll
        for (int k = 0; k < 4; ++k) {
            o[2 * k]     = lo[sel + k];
            o[2 * k + 1] = hi[sel + k];
        }
        *reinterpret_cast<bf16x8*>(fr + c * 6920 + px * 8) = o;
    }

    // ---- A fragments (m5 = relu(m - tau)) straight from global ----
    float t8[8];
    #pragma unroll
    for (int k = 0; k < 8; ++k) t8[k] = tau[g * 8 + k];
    const bf16* mb = m + (size_t)b * NPIX * 32;
    bf16x8 A[2];
    #pragma unroll
    for (int u = 0; u < 2; ++u) {
        int px = (w * 2 + u) * 16 + col;
        int y = y0 + (px >> 6), x = x0 + (px & 63);
        bf16x8 v = *reinterpret_cast<const bf16x8*>(mb + ((size_t)y * WW + x) * 32 + g * 8);
        #pragma unroll
        for (int k = 0; k < 8; ++k)
            v[k] = (bf16)fmaxf((float)v[k] - t8[k], 0.0f);
        A[u] = v;
    }
    __syncthreads();

    bf16* pb = pred + (size_t)b * NPIX * 128;

    #pragma unroll 1
    for (int half = 0; half < 2; ++half) {       // rates {1,2} then {3,4}
        float acc[2][2][8];
        #pragma unroll
        for (int u = 0; u < 2; ++u)
            #pragma unroll
            for (int r = 0; r < 2; ++r)
                #pragma unroll
                for (int k = 0; k < 8; ++k) acc[u][r][k] = 0.0f;

        #pragma unroll
        for (int tap = 0; tap < 9; ++tap) {
            const int dy = tap / 3 - 1, dx = tap % 3 - 1;
            bf16x8 B0 = *reinterpret_cast<const bf16x8*>(Wcore + tap * 1024 + col * 32 + g * 8);
            bf16x8 B1 = *reinterpret_cast<const bf16x8*>(Wcore + tap * 1024 + (16 + col) * 32 + g * 8);
            const float bv0 = b_outc[col * 9 + tap];
            const float bv1 = b_outc[(16 + col) * 9 + tap];

            #pragma unroll
            for (int u = 0; u < 2; ++u) {
                f32x4 c0 = {bv0, bv0, bv0, bv0};
                f32x4 c1 = {bv1, bv1, bv1, bv1};
                c0 = __builtin_amdgcn_mfma_f32_16x16x32_bf16(A[u], B0, c0, 0, 0, 0);
                c1 = __builtin_amdgcn_mfma_f32_16x16x32_bf16(A[u], B1, c1, 0, 0, 0);
                #pragma unroll
                for (int j = 0; j < 4; ++j) {
                    union { unsigned uu; bf16 h[2]; } pk;
                    pk.h[0] = (bf16)c0[j];
                    pk.h[1] = (bf16)c1[j];
                    int px = (w * 2 + u) * 16 + g * 4 + j;
                    *reinterpret_cast<unsigned*>(coreb + px * 80 + col * 4) = pk.uu;
                }
            }

            // same-wave LDS write->read ordering guaranteed (wave-private rows)
            #pragma unroll
            for (int u = 0; u < 2; ++u) {
                const int px = (w * 2 + u) * 16 + col;
                const int py = px >> 6, pxx = px & 63;
                bf16x8 c8 = *reinterpret_cast<const bf16x8*>(coreb + px * 80 + g * 16);
                float cf[8];
                #pragma unroll
                for (int k = 0; k < 8; ++k) cf[k] = (float)c8[k];
                #pragma unroll
                for (int r = 0; r < 2; ++r) {
                    const int R = half * 2 + r + 1;
                    const int row = py + 4 + dy * R, ccl = pxx + 4 + dx * R;
                    bf16x8 f8 = *reinterpret_cast<const bf16x8*>(fr + g * 6920 + (row * 72 + ccl) * 8);
                    #pragma unroll
                    for (int k = 0; k < 8; ++k)
                        acc[u][r][k] += cf[k] * (float)f8[k];
                }
            }
        }

        #pragma unroll
        for (int u = 0; u < 2; ++u) {
            const int px = (w * 2 + u) * 16 + col;
            const int y = y0 + (px >> 6), x = px & 63;
            #pragma unroll
            for (int r = 0; r < 2; ++r) {
                bf16x8 o;
                #pragma unroll
                for (int k = 0; k < 8; ++k) o[k] = (bf16)acc[u][r][k];
                *reinterpret_cast<bf16x8*>(
                    pb + ((size_t)y * WW + x0 + x) * 128 + (half * 2 + r) * 32 + g * 8) = o;
            }
        }
    }
}

// ---------------------------------------------------------------------------
extern "C" void kernel_launch(void* const* d_in, const int* in_sizes, int n_in,
                              void* d_out, int out_size, void* d_ws, size_t ws_size,
                              hipStream_t stream) {
    const float* input    = (const float*)d_in[0];
    const float* wconv    = (const float*)d_in[1];
    const float* bconv    = (const float*)d_in[2];
    const float* bn_gamma = (const float*)d_in[3];
    const float* bn_beta  = (const float*)d_in[4];
    const float* bn_mean  = (const float*)d_in[5];
    const float* bn_var   = (const float*)d_in[6];
    const float* tau      = (const float*)d_in[7];
    const float* w_outc   = (const float*)d_in[8];
    const float* b_outc   = (const float*)d_in[9];
    const float* w_final  = (const float*)d_in[10];
    const float* b_final  = (const float*)d_in[11];
    float* out = (float*)d_out;

    char* ws = (char*)d_ws;
    bf16*  Wres  = (bf16*)(ws);
    float* Bres  = (float*)(ws + 147456);
    bf16*  Wcore = (bf16*)(ws + 148480);
    bf16*  Wfin  = (bf16*)(ws + 166912);
    bf16*  in0b  = (bf16*)(ws + 240640);
    bf16*  actA  = (bf16*)(ws + 240640 + 16777216ull);
    bf16*  actB  = (bf16*)(ws + 240640 + 2 * 16777216ull);
    bf16*  actC  = (bf16*)(ws + 240640 + 3 * 16777216ull);
    bf16*  pred  = (bf16*)(ws + 240640 + 4 * 16777216ull);

    hipFuncSetAttribute(reinterpret_cast<const void*>(&core_pred_v3),
                        hipFuncAttributeMaxDynamicSharedMemorySize, 75840);

    prep_in<<<1024, 256, 0, stream>>>(input, in0b);
    fold_w<<<470, 256, 0, stream>>>(wconv, bconv, bn_gamma, bn_beta, bn_mean, bn_var,
                                    w_outc, w_final, Wres, Bres, Wcore, Wfin);

    dim3 grid(4, 32, 4), blk(256);
    conv3x3_mfma<false><<<grid, blk, 0, stream>>>(in0b, Wres + 0 * 9216, Bres + 0,   nullptr, actA);
    conv3x3_mfma<true ><<<grid, blk, 0, stream>>>(actA, Wres + 1 * 9216, Bres + 32,  in0b,    actB);
    conv3x3_mfma<false><<<grid, blk, 0, stream>>>(actB, Wres + 2 * 9216, Bres + 64,  nullptr, actA);
    conv3x3_mfma<true ><<<grid, blk, 0, stream>>>(actA, Wres + 3 * 9216, Bres + 96,  actB,    actC);
    conv3x3_mfma<false><<<grid, blk, 0, stream>>>(actC, Wres + 4 * 9216, Bres + 128, nullptr, actA);
    conv3x3_mfma<true ><<<grid, blk, 0, stream>>>(actA, Wres + 5 * 9216, Bres + 160, actC,    actB);
    conv3x3_mfma<false><<<grid, blk, 0, stream>>>(actB, Wres + 6 * 9216, Bres + 192, nullptr, actA);
    conv3x3_mfma<true ><<<grid, blk, 0, stream>>>(actA, Wres + 7 * 9216, Bres + 224, actB,    actC);

    dim3 gridp(4, 64, 4), blkp(512);
    core_pred_v3<<<gridp, blkp, 75840, stream>>>(actC, in0b, tau, Wcore, b_outc, pred);

    final_conv_mfma<<<grid, blk, 0, stream>>>(pred, Wfin, b_final, out);
}

// Round 6
// 225.608 us; speedup vs baseline: 2.4600x; 1.3452x over previous
//
#include <hip/hip_runtime.h>

typedef __bf16 bf16;
typedef __attribute__((ext_vector_type(8))) __bf16 bf16x8;
typedef __attribute__((ext_vector_type(4))) float f32x4;

#define HH 256
#define WW 256
#define BB 4
#define NPIX 65536

__device__ inline bf16x8 bzero8() {
    bf16x8 v;
    #pragma unroll
    for (int i = 0; i < 8; ++i) v[i] = (bf16)0.0f;
    return v;
}

// ---------------------------------------------------------------------------
// input NCHW fp32 -> in0b (NHWC bf16, true channel order)
//                 -> framesP (NHWC bf16, slot-permuted: slot s holds channel
//                    ch(s) = 4*(s>>3) + 16*((s>>2)&1) + (s&3))
// ---------------------------------------------------------------------------
__global__ __launch_bounds__(256) void prep_in(const float* __restrict__ in,
                                               bf16* __restrict__ out,
                                               bf16* __restrict__ framesP) {
    int p = blockIdx.x * 256 + threadIdx.x;
    int b = p >> 16, rem = p & 65535;
    float ch[32];
    #pragma unroll
    for (int c = 0; c < 32; ++c)
        ch[c] = in[(size_t)(b * 32 + c) * NPIX + rem];
    #pragma unroll
    for (int g = 0; g < 4; ++g) {
        bf16x8 v, w;
        #pragma unroll
        for (int j = 0; j < 8; ++j) v[j] = (bf16)ch[g * 8 + j];
        #pragma unroll
        for (int j = 0; j < 4; ++j) {
            w[j]     = (bf16)ch[4 * g + j];
            w[4 + j] = (bf16)ch[16 + 4 * g + j];
        }
        *reinterpret_cast<bf16x8*>(out + (size_t)p * 32 + g * 8) = v;
        *reinterpret_cast<bf16x8*>(framesP + (size_t)p * 32 + g * 8) = w;
    }
}

// ---------------------------------------------------------------------------
// Fold BN into conv weights; core weights [tap][n][ci]; core bias [tap][n];
// final weights [chunk(r) 4][tap 9][co 32][ci_slot 32] with
// ci_slot -> channel ch(s) = 4*(s>>3) + 16*((s>>2)&1) + (s&3).
// ---------------------------------------------------------------------------
__global__ void fold_w(const float* __restrict__ wconv, const float* __restrict__ bconv,
                       const float* __restrict__ g, const float* __restrict__ beta,
                       const float* __restrict__ mu, const float* __restrict__ var,
                       const float* __restrict__ w_outc, const float* __restrict__ b_outc,
                       const float* __restrict__ w_final,
                       bf16* __restrict__ Wres, float* __restrict__ Bres,
                       bf16* __restrict__ Wcore, bf16* __restrict__ Wfin,
                       float* __restrict__ bCore) {
    int idx = blockIdx.x * 256 + threadIdx.x;
    if (idx < 73728) {
        int l = idx / 9216, r = idx % 9216;
        int tap = r >> 10, co = (r >> 5) & 31, ci = r & 31;
        float s = g[l * 32 + co] * rsqrtf(var[l * 32 + co] + 1e-5f);
        Wres[idx] = (bf16)(wconv[l * 9216 + (co * 32 + ci) * 9 + tap] * s);
    } else if (idx < 73984) {
        int i = idx - 73728;
        float s = g[i] * rsqrtf(var[i] + 1e-5f);
        Bres[i] = (bconv[i] - mu[i]) * s + beta[i];
    } else if (idx < 83200) {
        int r = idx - 73984;
        int tap = r >> 10, nn = (r >> 5) & 31, ci = r & 31;
        Wcore[r] = (bf16)w_outc[(nn * 9 + tap) * 32 + ci];
    } else if (idx < 120064) {
        int r = idx - 83200;
        int chunk = r / 9216, r2 = r % 9216;
        int tap = r2 >> 10, co = (r2 >> 5) & 31, ci = r2 & 31;
        int n = 4 * (ci >> 3) + 16 * ((ci >> 2) & 1) + (ci & 3);  // slot -> channel
        Wfin[r] = (bf16)w_final[(size_t)(co * 128 + chunk * 32 + n) * 9 + tap];
    } else if (idx < 120352) {
        int r = idx - 120064;       // tap*32 + n
        int tap = r >> 5, n = r & 31;
        bCore[r] = b_outc[n * 9 + tap];
    }
}

// ---------------------------------------------------------------------------
// conv3x3 (32->32) MFMA implicit GEMM, NHWC bf16, BN folded, +resid, ReLU
// ---------------------------------------------------------------------------
template <bool RESID>
__global__ __launch_bounds__(256) void conv3x3_mfma(
    const bf16* __restrict__ in, const bf16* __restrict__ wB,
    const float* __restrict__ bias, const bf16* __restrict__ resid,
    bf16* __restrict__ out) {
    __shared__ bf16 tile[10 * 66 * 40];
    const int x0 = blockIdx.x * 64, y0 = blockIdx.y * 8, b = blockIdx.z;
    const int tid = threadIdx.x;
    const int lane = tid & 63, wv = tid >> 6;
    const int col = lane & 15, gq = lane >> 4;

    bf16x8 Bf[9][2];
    #pragma unroll
    for (int tap = 0; tap < 9; ++tap)
        #pragma unroll
        for (int cb = 0; cb < 2; ++cb)
            Bf[tap][cb] = *reinterpret_cast<const bf16x8*>(
                wB + tap * 1024 + (cb * 16 + col) * 32 + gq * 8);
    const float b0 = bias[col], b1 = bias[16 + col];

    const bf16* inb = in + (size_t)b * NPIX * 32;
    for (int i = tid; i < 2640; i += 256) {
        int yy = i / 264, r = i % 264;
        int xx = r >> 2, cg = r & 3;
        int gy = y0 + yy - 1, gx = x0 + xx - 1;
        bf16x8 v = bzero8();
        if ((unsigned)gy < HH && (unsigned)gx < WW)
            v = *reinterpret_cast<const bf16x8*>(inb + ((size_t)gy * WW + gx) * 32 + cg * 8);
        *reinterpret_cast<bf16x8*>(&tile[(yy * 66 + xx) * 40 + cg * 8]) = v;
    }

    f32x4 acc[8][2];
    #pragma unroll
    for (int m = 0; m < 8; ++m) {
        acc[m][0] = {b0, b0, b0, b0};
        acc[m][1] = {b1, b1, b1, b1};
    }
    __syncthreads();

    #pragma unroll
    for (int m = 0; m < 8; ++m) {
        const int row = 2 * wv + (m >> 2), xb = m & 3;
        #pragma unroll
        for (int tap = 0; tap < 9; ++tap) {
            const int dy = tap / 3, dx = tap % 3;
            bf16x8 A = *reinterpret_cast<const bf16x8*>(
                &tile[((row + dy) * 66 + xb * 16 + col + dx) * 40 + gq * 8]);
            acc[m][0] = __builtin_amdgcn_mfma_f32_16x16x32_bf16(A, Bf[tap][0], acc[m][0], 0, 0, 0);
            acc[m][1] = __builtin_amdgcn_mfma_f32_16x16x32_bf16(A, Bf[tap][1], acc[m][1], 0, 0, 0);
        }
    }

    bf16* outb = out + (size_t)b * NPIX * 32;
    const bf16* resb = RESID ? (resid + (size_t)b * NPIX * 32) : nullptr;
    #pragma unroll
    for (int m = 0; m < 8; ++m) {
        const int y = y0 + 2 * wv + (m >> 2);
        const int xbase = x0 + (m & 3) * 16 + gq * 4;
        #pragma unroll
        for (int cb = 0; cb < 2; ++cb) {
            const int co = cb * 16 + col;
            #pragma unroll
            for (int j = 0; j < 4; ++j) {
                size_t a = ((size_t)y * WW + xbase + j) * 32 + co;
                float v = acc[m][cb][j];
                if (RESID) v += (float)resb[a];
                outb[a] = (bf16)fmaxf(v, 0.0f);
            }
        }
    }
}

// ---------------------------------------------------------------------------
// final conv3x3 (128->32), 4 ci-chunks, out fp32 NCHW
// ---------------------------------------------------------------------------
__global__ __launch_bounds__(256) void final_conv_mfma(
    const bf16* __restrict__ pred, const bf16* __restrict__ Wfin,
    const float* __restrict__ bfin, float* __restrict__ out) {
    __shared__ bf16 tile[10 * 66 * 40];
    const int x0 = blockIdx.x * 64, y0 = blockIdx.y * 8, b = blockIdx.z;
    const int tid = threadIdx.x;
    const int lane = tid & 63, wv = tid >> 6;
    const int col = lane & 15, gq = lane >> 4;

    const float b0 = bfin[col], b1 = bfin[16 + col];
    f32x4 acc[8][2];
    #pragma unroll
    for (int m = 0; m < 8; ++m) {
        acc[m][0] = {b0, b0, b0, b0};
        acc[m][1] = {b1, b1, b1, b1};
    }

    for (int chunk = 0; chunk < 4; ++chunk) {
        if (chunk) __syncthreads();
        const bf16* inb = pred + (size_t)b * NPIX * 128 + chunk * 32;
        for (int i = tid; i < 2640; i += 256) {
            int yy = i / 264, r = i % 264;
            int xx = r >> 2, cg = r & 3;
            int gy = y0 + yy - 1, gx = x0 + xx - 1;
            bf16x8 v = bzero8();
            if ((unsigned)gy < HH && (unsigned)gx < WW)
                v = *reinterpret_cast<const bf16x8*>(inb + ((size_t)gy * WW + gx) * 128 + cg * 8);
            *reinterpret_cast<bf16x8*>(&tile[(yy * 66 + xx) * 40 + cg * 8]) = v;
        }
        bf16x8 Bf[9][2];
        #pragma unroll
        for (int tap = 0; tap < 9; ++tap)
            #pragma unroll
            for (int cb = 0; cb < 2; ++cb)
                Bf[tap][cb] = *reinterpret_cast<const bf16x8*>(
                    Wfin + chunk * 9216 + tap * 1024 + (cb * 16 + col) * 32 + gq * 8);
        __syncthreads();

        #pragma unroll
        for (int m = 0; m < 8; ++m) {
            const int row = 2 * wv + (m >> 2), xb = m & 3;
            #pragma unroll
            for (int tap = 0; tap < 9; ++tap) {
                const int dy = tap / 3, dx = tap % 3;
                bf16x8 A = *reinterpret_cast<const bf16x8*>(
                    &tile[((row + dy) * 66 + xb * 16 + col + dx) * 40 + gq * 8]);
                acc[m][0] = __builtin_amdgcn_mfma_f32_16x16x32_bf16(A, Bf[tap][0], acc[m][0], 0, 0, 0);
                acc[m][1] = __builtin_amdgcn_mfma_f32_16x16x32_bf16(A, Bf[tap][1], acc[m][1], 0, 0, 0);
            }
        }
    }

    #pragma unroll
    for (int m = 0; m < 8; ++m) {
        const int y = y0 + 2 * wv + (m >> 2);
        const int xbase = x0 + (m & 3) * 16 + gq * 4;
        #pragma unroll
        for (int cb = 0; cb < 2; ++cb) {
            const int co = cb * 16 + col;
            #pragma unroll
            for (int j = 0; j < 4; ++j)
                out[(size_t)(b * 32 + co) * NPIX + (size_t)y * WW + xbase + j] = acc[m][cb][j];
        }
    }
}

// ---------------------------------------------------------------------------
// core_pred v4: swapped-operand MFMA (A = Wcore rows n, B = m5 cols px).
// D: col = px = lane&15 (same px as the lane's B-frag!), row = n = 4g+j.
// Lane's 8 core values (2 halves) match frames slot-group g of the permuted
// framesP layout -> one ds_read_b128 per (tap, rate). No LDS transpose, no
// barriers in the tap loop. Tile 16x16 px, 256 thr, wave = 4 rows.
// ---------------------------------------------------------------------------
__global__ __launch_bounds__(256, 2) void core_pred_v4(
    const bf16* __restrict__ m, const bf16* __restrict__ framesP,
    const float* __restrict__ tau, const bf16* __restrict__ WcoreG,
    const float* __restrict__ bCore, bf16* __restrict__ pred) {
    __shared__ bf16 fr[576 * 32];      // [24y][24x][32 slots] = 36864 B
    __shared__ bf16 Wc[9 * 32 * 32];   // [tap][n][c]          = 18432 B
    const int x0 = blockIdx.x * 16, y0 = blockIdx.y * 16, b = blockIdx.z;
    const int tid = threadIdx.x;
    const int lane = tid & 63, wv = tid >> 6;
    const int col = lane & 15, g = lane >> 4;

    // stage Wcore
    for (int i = tid; i < 1152; i += 256)
        *reinterpret_cast<bf16x8*>(Wc + i * 8) =
            *reinterpret_cast<const bf16x8*>(WcoreG + i * 8);
    // stage frames tile (permuted NHWC, halo 4)
    const bf16* fb = framesP + (size_t)b * NPIX * 32;
    for (int i = tid; i < 2304; i += 256) {
        int px = i >> 2, cg = i & 3;
        int yy = px / 24, xx = px % 24;
        int gy = y0 + yy - 4, gx = x0 + xx - 4;
        bf16x8 v = bzero8();
        if ((unsigned)gy < HH && (unsigned)gx < WW)
            v = *reinterpret_cast<const bf16x8*>(fb + ((size_t)gy * WW + gx) * 32 + cg * 8);
        *reinterpret_cast<bf16x8*>(fr + px * 32 + cg * 8) = v;
    }
    float t8[8];
    #pragma unroll
    for (int k = 0; k < 8; ++k) t8[k] = tau[g * 8 + k];
    __syncthreads();

    const bf16* mb = m + (size_t)b * NPIX * 32;
    bf16* pb = pred + (size_t)b * NPIX * 128;

    #pragma unroll 1
    for (int uu = 0; uu < 4; ++uu) {
        const int yl = wv * 4 + uu;            // local row 0..15
        const int y = y0 + yl;

        // B-frag: m5[px = x0+col][c = 8g..8g+7]
        bf16x8 Bv = *reinterpret_cast<const bf16x8*>(
            mb + ((size_t)y * WW + x0 + col) * 32 + g * 8);
        #pragma unroll
        for (int k = 0; k < 8; ++k)
            Bv[k] = (bf16)fmaxf((float)Bv[k] - t8[k], 0.0f);

        float acc[4][8];
        #pragma unroll
        for (int r = 0; r < 4; ++r)
            #pragma unroll
            for (int k = 0; k < 8; ++k) acc[r][k] = 0.0f;

        #pragma unroll
        for (int dy = 0; dy < 3; ++dy) {
            float core[3][8];
            #pragma unroll
            for (int dx = 0; dx < 3; ++dx) {
                const int tap = dy * 3 + dx;
                bf16x8 A0 = *reinterpret_cast<const bf16x8*>(
                    Wc + tap * 1024 + col * 32 + g * 8);
                bf16x8 A1 = *reinterpret_cast<const bf16x8*>(
                    Wc + tap * 1024 + (16 + col) * 32 + g * 8);
                f32x4 c0 = *reinterpret_cast<const f32x4*>(bCore + tap * 32 + 4 * g);
                f32x4 c1 = *reinterpret_cast<const f32x4*>(bCore + tap * 32 + 16 + 4 * g);
                c0 = __builtin_amdgcn_mfma_f32_16x16x32_bf16(A0, Bv, c0, 0, 0, 0);
                c1 = __builtin_amdgcn_mfma_f32_16x16x32_bf16(A1, Bv, c1, 0, 0, 0);
                #pragma unroll
                for (int j = 0; j < 4; ++j) {
                    core[dx][j]     = c0[j];
                    core[dx][4 + j] = c1[j];
                }
            }
            #pragma unroll
            for (int r = 1; r <= 4; ++r) {
                const int row = yl + 4 + (dy - 1) * r;
                #pragma unroll
                for (int dx = 0; dx < 3; ++dx) {
                    const int cc = col + 4 + (dx - 1) * r;
                    bf16x8 f8 = *reinterpret_cast<const bf16x8*>(
                        fr + (row * 24 + cc) * 32 + g * 8);
                    #pragma unroll
                    for (int k = 0; k < 8; ++k)
                        acc[r - 1][k] += core[dx][k] * (float)f8[k];
                }
            }
        }

        #pragma unroll
        for (int r = 0; r < 4; ++r) {
            bf16x8 o;
            #pragma unroll
            for (int k = 0; k < 8; ++k) o[k] = (bf16)acc[r][k];
            *reinterpret_cast<bf16x8*>(
                pb + ((size_t)y * WW + x0 + col) * 128 + r * 32 + g * 8) = o;
        }
    }
}

// ---------------------------------------------------------------------------
extern "C" void kernel_launch(void* const* d_in, const int* in_sizes, int n_in,
                              void* d_out, int out_size, void* d_ws, size_t ws_size,
                              hipStream_t stream) {
    const float* input    = (const float*)d_in[0];
    const float* wconv    = (const float*)d_in[1];
    const float* bconv    = (const float*)d_in[2];
    const float* bn_gamma = (const float*)d_in[3];
    const float* bn_beta  = (const float*)d_in[4];
    const float* bn_mean  = (const float*)d_in[5];
    const float* bn_var   = (const float*)d_in[6];
    const float* tau      = (const float*)d_in[7];
    const float* w_outc   = (const float*)d_in[8];
    const float* b_outc   = (const float*)d_in[9];
    const float* w_final  = (const float*)d_in[10];
    const float* b_final  = (const float*)d_in[11];
    float* out = (float*)d_out;

    char* ws = (char*)d_ws;
    bf16*  Wres  = (bf16*)(ws);                        // [0, 147456)
    float* Bres  = (float*)(ws + 147456);              // [147456, 148480)
    bf16*  Wcore = (bf16*)(ws + 148480);               // [148480, 166912)
    bf16*  Wfin  = (bf16*)(ws + 166912);               // [166912, 240640)
    float* bCore = (float*)(ws + 240640);              // [240640, 241792) + pad
    bf16*  in0b    = (bf16*)(ws + 245760);             // 16 MB each below
    bf16*  framesP = (bf16*)(ws + 245760 + 16777216ull);
    bf16*  actA    = (bf16*)(ws + 245760 + 2 * 16777216ull);
    bf16*  actB    = (bf16*)(ws + 245760 + 3 * 16777216ull);
    bf16*  actC    = (bf16*)(ws + 245760 + 4 * 16777216ull);
    bf16*  pred    = (bf16*)(ws + 245760 + 5 * 16777216ull);  // 67108864 B

    prep_in<<<1024, 256, 0, stream>>>(input, in0b, framesP);
    fold_w<<<471, 256, 0, stream>>>(wconv, bconv, bn_gamma, bn_beta, bn_mean, bn_var,
                                    w_outc, b_outc, w_final,
                                    Wres, Bres, Wcore, Wfin, bCore);

    dim3 grid(4, 32, 4), blk(256);
    conv3x3_mfma<false><<<grid, blk, 0, stream>>>(in0b, Wres + 0 * 9216, Bres + 0,   nullptr, actA);
    conv3x3_mfma<true ><<<grid, blk, 0, stream>>>(actA, Wres + 1 * 9216, Bres + 32,  in0b,    actB);
    conv3x3_mfma<false><<<grid, blk, 0, stream>>>(actB, Wres + 2 * 9216, Bres + 64,  nullptr, actA);
    conv3x3_mfma<true ><<<grid, blk, 0, stream>>>(actA, Wres + 3 * 9216, Bres + 96,  actB,    actC);
    conv3x3_mfma<false><<<grid, blk, 0, stream>>>(actC, Wres + 4 * 9216, Bres + 128, nullptr, actA);
    conv3x3_mfma<true ><<<grid, blk, 0, stream>>>(actA, Wres + 5 * 9216, Bres + 160, actC,    actB);
    conv3x3_mfma<false><<<grid, blk, 0, stream>>>(actB, Wres + 6 * 9216, Bres + 192, nullptr, actA);
    conv3x3_mfma<true ><<<grid, blk, 0, stream>>>(actA, Wres + 7 * 9216, Bres + 224, actB,    actC);

    dim3 gridp(16, 16, 4);
    core_pred_v4<<<gridp, blk, 0, stream>>>(actC, framesP, tau, Wcore, bCore, pred);

    final_conv_mfma<<<grid, blk, 0, stream>>>(pred, Wfin, b_final, out);
}